// Round 11
// baseline (1158.199 us; speedup 1.0000x reference)
//
#include <hip/hip_runtime.h>
#include <cstdint>

// ---------------------------------------------------------------------------
// RGCN (flight/airport heterograph).
// bf16 activation storage; all GEMMs on MFMA (bf16 in, fp32 accum).
// Per layer, per node type, per chunk:
//   Aagg = [agg_relA | agg_relB]  (K=512, bf16)  (gather, chunk-local)
//   acc  = [Aagg | x_cur] @ Bt^T + bias
//          (A & B tiles staged via global_load_lds (async DMA, no VGPR),
//           double-buffered, BK=32, swizzled-source + swizzled ds_read)
//   x_nxt = leaky(LN(acc)) + x_cur        (fused epilogue, no h buffer)
// x buffers ping-pong per layer -> gathers always read an immutable x_cur.
// CSR built on-device once per call (count -> scan -> fill).
// ---------------------------------------------------------------------------

namespace {

constexpr int kNF = 100000;
constexpr int kNA = 4000;
constexpr int kN  = 104000;
constexpr int kH  = 256;
constexpr int kL  = 4;
constexpr int kB  = 3;
constexpr int kEFA = 200000;
constexpr int kEAF = 200000;
constexpr int kEFF = 400000;
constexpr int kEAA = 40000;
constexpr int kETOT = 840000;
constexpr int kK = 768;   // logical concat K: 2 agg slots + x
constexpr int kKA = 512;  // Aagg row width
// segment space (concatenated per-relation dst ranges):
// r0 fa->airport [0,kNA) | r1 af->flight [kNA,kNA+kNF)
// r2 ff->flight [kNA+kNF, kNA+2kNF) | r3 aa->airport [kNA+2kNF, kSEG)
constexpr int kSEG = 2 * kNA + 2 * kNF;           // 208000
constexpr int kScanBlocks = (kSEG + 1023) / 1024; // 204

typedef __attribute__((ext_vector_type(8))) short short8v;
typedef __attribute__((ext_vector_type(4))) float float4v;

__device__ __forceinline__ float b2f(unsigned short u) {
  union { unsigned int i; float f; } v;
  v.i = ((unsigned int)u) << 16;
  return v.f;
}
__device__ __forceinline__ unsigned short f2b(float f) {
  union { float f; unsigned int i; } v;
  v.f = f;
  unsigned int x = v.i;
  x += 0x7fffu + ((x >> 16) & 1u);  // round-to-nearest-even
  return (unsigned short)(x >> 16);
}

// async global->LDS, 16 bytes per lane; dst is wave-uniform base, lane i
// lands at dst + i*16.
__device__ __forceinline__ void gload16(const unsigned short* gsrc,
                                        unsigned short* lds) {
  __builtin_amdgcn_global_load_lds(
      (const __attribute__((address_space(1))) unsigned int*)gsrc,
      (__attribute__((address_space(3))) unsigned int*)lds, 16, 0, 0);
}

// ---------------------------------------------------------------------------
// Encoder weight transpose+pad: Wt[n][k] (bf16, k padded to 32)
// ---------------------------------------------------------------------------
__global__ void k_build_encWt(const float* __restrict__ wf,
                              const float* __restrict__ wa,
                              unsigned short* __restrict__ WtF,
                              unsigned short* __restrict__ WtA) {
  const int idx = blockIdx.x * 256 + threadIdx.x;
  if (idx >= 2 * kH * 32) return;
  const int t = idx / (kH * 32);
  const int rem = idx % (kH * 32);
  const int n = rem >> 5;
  const int k = rem & 31;
  if (t == 0) {
    WtF[n * 32 + k] = f2b(wf[k * kH + n]);
  } else {
    WtA[n * 32 + k] = (k < 16) ? f2b(wa[k * kH + n]) : (unsigned short)0;
  }
}

// ---------------------------------------------------------------------------
// MFMA encoder: xout[rowoff+r] = xin[r] @ W + bias  (Wt [256][32] bf16)
// ---------------------------------------------------------------------------
template <int KIN>
__global__ __launch_bounds__(256) void k_enc_mfma(
    const float* __restrict__ xin, const unsigned short* __restrict__ Wt,
    const float* __restrict__ bias, unsigned short* __restrict__ xout, int M,
    int rowoff) {
  __shared__ __align__(16) unsigned short As[64][40];
  const int tid = threadIdx.x;
  const int wave = tid >> 6;
  const int lane = tid & 63;
  const int fr = lane & 15;
  const int fq = lane >> 4;
  const int ncol0 = wave * 64;
  const int brow = blockIdx.x * 64;

  const int row = tid >> 2;
  const int col0 = (tid & 3) * 8;
  float4 f0 = make_float4(0.f, 0.f, 0.f, 0.f);
  float4 f1 = make_float4(0.f, 0.f, 0.f, 0.f);
  if (brow + row < M) {
    if (col0 < KIN) f0 = *(const float4*)&xin[(size_t)(brow + row) * KIN + col0];
    if (col0 + 4 < KIN)
      f1 = *(const float4*)&xin[(size_t)(brow + row) * KIN + col0 + 4];
  }
  uint4 packed;
  packed.x = (unsigned int)f2b(f0.x) | ((unsigned int)f2b(f0.y) << 16);
  packed.y = (unsigned int)f2b(f0.z) | ((unsigned int)f2b(f0.w) << 16);
  packed.z = (unsigned int)f2b(f1.x) | ((unsigned int)f2b(f1.y) << 16);
  packed.w = (unsigned int)f2b(f1.z) | ((unsigned int)f2b(f1.w) << 16);
  *(uint4*)&As[row][col0] = packed;
  __syncthreads();

  short8v bfrag[4];
#pragma unroll
  for (int ni = 0; ni < 4; ++ni)
    bfrag[ni] = *(const short8v*)&Wt[(size_t)(ncol0 + ni * 16 + fr) * 32 + fq * 8];

  float4v acc[4][4];
#pragma unroll
  for (int mi = 0; mi < 4; ++mi) {
    const short8v afrag = *(const short8v*)&As[mi * 16 + fr][fq * 8];
#pragma unroll
    for (int ni = 0; ni < 4; ++ni)
      acc[mi][ni] = __builtin_amdgcn_mfma_f32_16x16x32_bf16(
          afrag, bfrag[ni], (float4v)(0.f), 0, 0, 0);
  }

#pragma unroll
  for (int ni = 0; ni < 4; ++ni) {
    const int col = ncol0 + ni * 16 + fr;
    const float bb = bias[col];
#pragma unroll
    for (int mi = 0; mi < 4; ++mi) {
      const int row0 = brow + mi * 16 + fq * 4;
#pragma unroll
      for (int reg = 0; reg < 4; ++reg) {
        const int r = row0 + reg;
        if (r < M) xout[(size_t)(rowoff + r) * kH + col] = f2b(acc[mi][ni][reg] + bb);
      }
    }
  }
}

// ---------------------------------------------------------------------------
// CSR build (all relations in one dispatch)
// ---------------------------------------------------------------------------
__device__ __forceinline__ void edge_decode(int i, const int* ei_fa,
                                            const int* ei_af, const int* ei_ff,
                                            const int* ei_aa, int& src,
                                            int& dstseg) {
  if (i < kEFA) {
    src = ei_fa[i];
    dstseg = 0 + ei_fa[kEFA + i];
  } else if (i < kEFA + kEAF) {
    const int j = i - kEFA;
    src = kNF + ei_af[j];
    dstseg = kNA + ei_af[kEAF + j];
  } else if (i < kEFA + kEAF + kEFF) {
    const int j = i - kEFA - kEAF;
    src = ei_ff[j];
    dstseg = kNA + kNF + ei_ff[kEFF + j];
  } else {
    const int j = i - kEFA - kEAF - kEFF;
    src = kNF + ei_aa[j];
    dstseg = kNA + 2 * kNF + ei_aa[kEAA + j];
  }
}

__global__ void k_count_all(const int* __restrict__ ei_fa,
                            const int* __restrict__ ei_af,
                            const int* __restrict__ ei_ff,
                            const int* __restrict__ ei_aa,
                            int* __restrict__ cnt) {
  const int i = blockIdx.x * 256 + threadIdx.x;
  if (i >= kETOT) return;
  int src, dstseg;
  edge_decode(i, ei_fa, ei_af, ei_ff, ei_aa, src, dstseg);
  atomicAdd(&cnt[dstseg], 1);
}

__global__ void k_scan1(const int* __restrict__ cnt, int* __restrict__ out,
                        int* __restrict__ bsum, float* __restrict__ invdeg) {
  __shared__ int sh[256];
  const int tid = threadIdx.x;
  const int base = blockIdx.x * 1024 + tid * 4;
  int v[4];
#pragma unroll
  for (int j = 0; j < 4; ++j) v[j] = (base + j < kSEG) ? cnt[base + j] : 0;
#pragma unroll
  for (int j = 0; j < 4; ++j)
    if (base + j < kSEG)
      invdeg[base + j] = 1.0f / (float)(v[j] > 0 ? v[j] : 1);
  const int tsum = v[0] + v[1] + v[2] + v[3];
  sh[tid] = tsum;
  __syncthreads();
  for (int o = 1; o < 256; o <<= 1) {
    int t = (tid >= o) ? sh[tid - o] : 0;
    __syncthreads();
    sh[tid] += t;
    __syncthreads();
  }
  const int excl = sh[tid] - tsum;
  int run = excl;
#pragma unroll
  for (int j = 0; j < 4; ++j) {
    if (base + j < kSEG) out[base + j] = run;
    run += v[j];
  }
  if (tid == 255) bsum[blockIdx.x] = sh[255];
}

__global__ void k_scan2(const int* __restrict__ bsum, int* __restrict__ bpre) {
  __shared__ int sh[256];
  const int tid = threadIdx.x;
  const int v = (tid < kScanBlocks) ? bsum[tid] : 0;
  sh[tid] = v;
  __syncthreads();
  for (int o = 1; o < 256; o <<= 1) {
    int t = (tid >= o) ? sh[tid - o] : 0;
    __syncthreads();
    sh[tid] += t;
    __syncthreads();
  }
  if (tid < kScanBlocks) bpre[tid] = sh[tid] - v;
}

__global__ void k_scan3(int* __restrict__ off, int* __restrict__ cursor,
                        const int* __restrict__ bpre) {
  const int i = blockIdx.x * 256 + threadIdx.x;
  if (i < kSEG) {
    const int val = off[i] + bpre[i >> 10];
    off[i] = val;
    cursor[i] = val;
  }
  if (i == 0) off[kSEG] = kETOT;
}

__global__ void k_fill_all(const int* __restrict__ ei_fa,
                           const int* __restrict__ ei_af,
                           const int* __restrict__ ei_ff,
                           const int* __restrict__ ei_aa,
                           int* __restrict__ cursor, int* __restrict__ elist) {
  const int i = blockIdx.x * 256 + threadIdx.x;
  if (i >= kETOT) return;
  int src, dstseg;
  edge_decode(i, ei_fa, ei_af, ei_ff, ei_aa, src, dstseg);
  const int pos = atomicAdd(&cursor[dstseg], 1);
  elist[pos] = src;
}

// ---------------------------------------------------------------------------
// Stacked transposed B build (bf16):
//   BtF[n][k] = ([W_r1; W_r2; root])[k][n],  BtA likewise with {r0, r3}.
// ---------------------------------------------------------------------------
__global__ void k_build_Bt(const float* __restrict__ comp_l,
                           const float* __restrict__ basis_l,
                           const float* __restrict__ root_l,
                           unsigned short* __restrict__ BtF,
                           unsigned short* __restrict__ BtA) {
  const int idx = blockIdx.x * 256 + threadIdx.x;
  if (idx >= 2 * kK * kH) return;
  const int t = idx / (kK * kH);
  const int rem = idx % (kK * kH);
  const int n = rem / kK;     // 0..255 output col
  const int k = rem % kK;     // 0..767
  const int slot = k >> 8;    // 0,1,2
  const int wrow = k & 255;
  float val;
  if (slot == 2) {
    val = root_l[wrow * kH + n];
  } else {
    const int r = (t == 0) ? (slot == 0 ? 1 : 2) : (slot == 0 ? 0 : 3);
    const int io = wrow * kH + n;
    val = comp_l[r * kB + 0] * basis_l[0 * kH * kH + io] +
          comp_l[r * kB + 1] * basis_l[1 * kH * kH + io] +
          comp_l[r * kB + 2] * basis_l[2 * kH * kH + io];
  }
  (t == 0 ? BtF : BtA)[(size_t)n * kK + k] = f2b(val);
}

// ---------------------------------------------------------------------------
// Gather-mean: Aagg[d][slot*256..] = mean_{src in CSR[d]} x[src]  (bf16)
// 32 lanes per destination (2 dsts per wave); blockIdx.y = slot (0/1).
// ---------------------------------------------------------------------------
__global__ __launch_bounds__(256) void k_gather2(
    const unsigned short* __restrict__ x, unsigned short* __restrict__ Aagg,
    const int* __restrict__ off, const int* __restrict__ elist,
    const float* __restrict__ invdeg, int segbase0, int segbase1, int c0,
    int nrows) {
  const int half = threadIdx.x >> 5;  // 0..7
  const int lane = threadIdx.x & 31;
  const int d = blockIdx.x * 8 + half;
  const int slot = blockIdx.y;
  if (d >= nrows) return;
  const int s = (slot == 0 ? segbase0 : segbase1) + c0 + d;
  const int lo = off[s], hi = off[s + 1];
  const float iv = invdeg[s];
  float a0 = 0.f, a1 = 0.f, a2 = 0.f, a3 = 0.f;
  float a4 = 0.f, a5 = 0.f, a6 = 0.f, a7 = 0.f;
  const unsigned short* xl = x + lane * 8;
  int e = lo;
  for (; e + 3 < hi; e += 4) {
    const int s0 = elist[e], s1 = elist[e + 1];
    const int s2 = elist[e + 2], s3 = elist[e + 3];
    const uint4 v0 = *(const uint4*)(xl + (size_t)s0 * kH);
    const uint4 v1 = *(const uint4*)(xl + (size_t)s1 * kH);
    const uint4 v2 = *(const uint4*)(xl + (size_t)s2 * kH);
    const uint4 v3 = *(const uint4*)(xl + (size_t)s3 * kH);
    a0 += b2f((unsigned short)v0.x) + b2f((unsigned short)v1.x) +
          b2f((unsigned short)v2.x) + b2f((unsigned short)v3.x);
    a1 += b2f((unsigned short)(v0.x >> 16)) + b2f((unsigned short)(v1.x >> 16)) +
          b2f((unsigned short)(v2.x >> 16)) + b2f((unsigned short)(v3.x >> 16));
    a2 += b2f((unsigned short)v0.y) + b2f((unsigned short)v1.y) +
          b2f((unsigned short)v2.y) + b2f((unsigned short)v3.y);
    a3 += b2f((unsigned short)(v0.y >> 16)) + b2f((unsigned short)(v1.y >> 16)) +
          b2f((unsigned short)(v2.y >> 16)) + b2f((unsigned short)(v3.y >> 16));
    a4 += b2f((unsigned short)v0.z) + b2f((unsigned short)v1.z) +
          b2f((unsigned short)v2.z) + b2f((unsigned short)v3.z);
    a5 += b2f((unsigned short)(v0.z >> 16)) + b2f((unsigned short)(v1.z >> 16)) +
          b2f((unsigned short)(v2.z >> 16)) + b2f((unsigned short)(v3.z >> 16));
    a6 += b2f((unsigned short)v0.w) + b2f((unsigned short)v1.w) +
          b2f((unsigned short)v2.w) + b2f((unsigned short)v3.w);
    a7 += b2f((unsigned short)(v0.w >> 16)) + b2f((unsigned short)(v1.w >> 16)) +
          b2f((unsigned short)(v2.w >> 16)) + b2f((unsigned short)(v3.w >> 16));
  }
  for (; e < hi; ++e) {
    const int s0 = elist[e];
    const uint4 v0 = *(const uint4*)(xl + (size_t)s0 * kH);
    a0 += b2f((unsigned short)v0.x);
    a1 += b2f((unsigned short)(v0.x >> 16));
    a2 += b2f((unsigned short)v0.y);
    a3 += b2f((unsigned short)(v0.y >> 16));
    a4 += b2f((unsigned short)v0.z);
    a5 += b2f((unsigned short)(v0.z >> 16));
    a6 += b2f((unsigned short)v0.w);
    a7 += b2f((unsigned short)(v0.w >> 16));
  }
  uint4 o;
  o.x = (unsigned int)f2b(a0 * iv) | ((unsigned int)f2b(a1 * iv) << 16);
  o.y = (unsigned int)f2b(a2 * iv) | ((unsigned int)f2b(a3 * iv) << 16);
  o.z = (unsigned int)f2b(a4 * iv) | ((unsigned int)f2b(a5 * iv) << 16);
  o.w = (unsigned int)f2b(a6 * iv) | ((unsigned int)f2b(a7 * iv) << 16);
  *(uint4*)&Aagg[(size_t)d * kKA + slot * kH + lane * 8] = o;
}

// ---------------------------------------------------------------------------
// Fused MFMA GEMM + LayerNorm + leaky + residual.
//   acc = [Aagg | xcur] @ Bt^T + bias   (K=768, BK=32, 24 K-tiles)
// A [64][32] and B [256][32] tiles staged via global_load_lds (async DMA,
// no VGPR), double-buffered. Source granules pre-swizzled (g ^= row&3) so
// the linear LDS + swizzled ds_read is <=4-way bank conflicted.
// 2-phase loop: STAGE(next) ; ds_read+MFMA(cur) ; __syncthreads (drains
// vmcnt -> next buffer ready; all reads of cur done before overwrite).
// Block: 256 thr (4 waves), tile 64 rows x 256 cols (wave w: cols w*64).
// ---------------------------------------------------------------------------
__global__ __launch_bounds__(256) void k_gemm_fused(
    const unsigned short* __restrict__ Aagg,
    const unsigned short* __restrict__ xcur, unsigned short* __restrict__ xnxt,
    const unsigned short* __restrict__ Bt, const float* __restrict__ bias,
    const float* __restrict__ gamma, const float* __restrict__ beta, int M,
    int grow0) {
  __shared__ __align__(16) unsigned short As[2][64][32];
  __shared__ __align__(16) unsigned short Bs[2][256][32];
  __shared__ float redS[4][64];
  __shared__ float redQ[4][64];
  __shared__ float stat[64][2];

  const int tid = threadIdx.x;
  const int wave = tid >> 6;
  const int lane = tid & 63;
  const int fr = lane & 15;
  const int fq = lane >> 4;
  const int ncol0 = wave * 64;
  const int brow = blockIdx.x * 64;

  // staging lane decomposition: 4 lanes per row (16B granules), 16 rows/instr
  const int srow = lane >> 2;                    // 0..15
  const int sg = (lane & 3) ^ (srow & 3);        // swizzled source granule
  // A: wave w stages rows w*16 .. w*16+15
  const int arow = wave * 16 + srow;
  const unsigned short* Asrc_agg = Aagg + (size_t)(brow + arow) * kKA + sg * 8;
  const unsigned short* Asrc_x =
      xcur + (size_t)(grow0 + brow + arow) * kH + sg * 8;
  unsigned short* Adst0 = &As[0][wave * 16][0];
  unsigned short* Adst1 = &As[1][wave * 16][0];
  // B: wave w stages rows w*64 + j*16 .. +15 (j = 0..3)
  const unsigned short* Bsrc = Bt + (size_t)(wave * 64 + srow) * kK + sg * 8;

#define STAGE(buf, t)                                                         \
  do {                                                                        \
    const int kb_ = (t) * 32;                                                 \
    gload16((kb_ < kKA) ? (Asrc_agg + kb_) : (Asrc_x + (kb_ - kKA)),          \
            (buf) ? Adst1 : Adst0);                                           \
    _Pragma("unroll") for (int j_ = 0; j_ < 4; ++j_)                          \
        gload16(Bsrc + (size_t)(j_ * 16) * kK + kb_,                          \
                &Bs[buf][wave * 64 + j_ * 16][0]);                            \
  } while (0)

  float4v acc[4][4];
#pragma unroll
  for (int mi = 0; mi < 4; ++mi)
#pragma unroll
    for (int ni = 0; ni < 4; ++ni) acc[mi][ni] = (float4v)(0.f);

  const int rg = (fr & 3);  // read-side swizzle component

  // prologue
  STAGE(0, 0);
  __syncthreads();

  for (int t = 0; t < 24; ++t) {
    const int cur = t & 1;
    if (t < 23) STAGE(cur ^ 1, t + 1);
    short8v afrag[4], bfrag[4];
#pragma unroll
    for (int mi = 0; mi < 4; ++mi)
      afrag[mi] = *(const short8v*)&As[cur][mi * 16 + fr][(fq ^ rg) * 8];
#pragma unroll
    for (int ni = 0; ni < 4; ++ni)
      bfrag[ni] =
          *(const short8v*)&Bs[cur][ncol0 + ni * 16 + fr][(fq ^ rg) * 8];
#pragma unroll
    for (int mi = 0; mi < 4; ++mi)
#pragma unroll
      for (int ni = 0; ni < 4; ++ni)
        acc[mi][ni] = __builtin_amdgcn_mfma_f32_16x16x32_bf16(
            afrag[mi], bfrag[ni], acc[mi][ni], 0, 0, 0);
    __syncthreads();  // drains this iter's gload_lds; cur reads all done
  }
#undef STAGE

  // ---- fused epilogue: bias, LN stats, leaky, residual, bf16 store ----
  float bb[4], gam[4], bet[4];
#pragma unroll
  for (int ni = 0; ni < 4; ++ni) {
    const int col = ncol0 + ni * 16 + fr;
    bb[ni] = bias[col];
    gam[ni] = gamma[col];
    bet[ni] = beta[col];
  }
#pragma unroll
  for (int mi = 0; mi < 4; ++mi)
#pragma unroll
    for (int ni = 0; ni < 4; ++ni)
#pragma unroll
      for (int reg = 0; reg < 4; ++reg) acc[mi][ni][reg] += bb[ni];

#pragma unroll
  for (int mi = 0; mi < 4; ++mi) {
#pragma unroll
    for (int reg = 0; reg < 4; ++reg) {
      float s = 0.f, q = 0.f;
#pragma unroll
      for (int ni = 0; ni < 4; ++ni) {
        const float v = acc[mi][ni][reg];
        s += v;
        q += v * v;
      }
#pragma unroll
      for (int o = 1; o < 16; o <<= 1) {
        s += __shfl_xor(s, o);
        q += __shfl_xor(q, o);
      }
      if (fr == 0) {
        const int rl = mi * 16 + fq * 4 + reg;
        redS[wave][rl] = s;
        redQ[wave][rl] = q;
      }
    }
  }
  __syncthreads();
  if (tid < 64) {
    const float s = redS[0][tid] + redS[1][tid] + redS[2][tid] + redS[3][tid];
    const float q = redQ[0][tid] + redQ[1][tid] + redQ[2][tid] + redQ[3][tid];
    const float mu = s * (1.f / kH);
    const float var = q * (1.f / kH) - mu * mu;
    stat[tid][0] = mu;
    stat[tid][1] = rsqrtf(var + 1e-5f);
  }
  __syncthreads();

#pragma unroll
  for (int mi = 0; mi < 4; ++mi) {
#pragma unroll
    for (int reg = 0; reg < 4; ++reg) {
      const int rl = mi * 16 + fq * 4 + reg;
      const int r = brow + rl;
      if (r >= M) continue;
      const float mu = stat[rl][0];
      const float rs = stat[rl][1];
      const size_t gr = (size_t)(grow0 + r) * kH;
#pragma unroll
      for (int ni = 0; ni < 4; ++ni) {
        const int col = ncol0 + ni * 16 + fr;
        float t = (acc[mi][ni][reg] - mu) * rs * gam[ni] + bet[ni];
        t = t > 0.f ? t : 0.1f * t;
        const float xo = b2f(xcur[gr + col]);
        xnxt[gr + col] = f2b(xo + t);
      }
    }
  }
}

// ---------------------------------------------------------------------------
// Readout: out[n] = dot(x[n], ro_w) + ro_b  (flight rows), fp32 out.
// ---------------------------------------------------------------------------
__global__ __launch_bounds__(256) void k_readout(
    const unsigned short* __restrict__ x, const float* __restrict__ w,
    const float* __restrict__ b, float* __restrict__ out) {
  const int wave = threadIdx.x >> 6;
  const int lane = threadIdx.x & 63;
  const int row = blockIdx.x * 4 + wave;
  if (row >= kNF) return;
  const ushort4 v = *(const ushort4*)&x[(size_t)row * kH + (lane << 2)];
  const float4 wv = *(const float4*)&w[lane << 2];
  float s = b2f(v.x) * wv.x + b2f(v.y) * wv.y + b2f(v.z) * wv.z +
            b2f(v.w) * wv.w;
#pragma unroll
  for (int o = 1; o < 64; o <<= 1) s += __shfl_xor(s, o);
  if (lane == 0) out[row] = s + b[0];
}

}  // namespace

// ---------------------------------------------------------------------------
extern "C" void kernel_launch(void* const* d_in, const int* in_sizes, int n_in,
                              void* d_out, int out_size, void* d_ws,
                              size_t ws_size, hipStream_t stream) {
  const float* x_flight = (const float*)d_in[0];
  const float* x_airport = (const float*)d_in[1];
  const float* enc_w_f = (const float*)d_in[2];
  const float* enc_b_f = (const float*)d_in[3];
  const float* enc_w_a = (const float*)d_in[4];
  const float* enc_b_a = (const float*)d_in[5];
  const float* basis = (const float*)d_in[6];
  const float* comp = (const float*)d_in[7];
  const float* root = (const float*)d_in[8];
  const float* conv_bias = (const float*)d_in[9];
  const float* ln_gamma = (const float*)d_in[10];
  const float* ln_beta = (const float*)d_in[11];
  const float* ro_w = (const float*)d_in[12];
  const float* ro_b = (const float*)d_in[13];
  const int* ei_fa = (const int*)d_in[14];
  const int* ei_af = (const int*)d_in[15];
  const int* ei_ff = (const int*)d_in[16];
  const int* ei_aa = (const int*)d_in[17];
  float* out = (float*)d_out;

  // workspace carve (fixed buffers first, then adaptive A-chunk)
  char* base = (char*)d_ws;
  size_t off_b = 0;
  auto carve = [&](size_t bytes) -> char* {
    char* p = base + off_b;
    off_b += (bytes + 255) & ~(size_t)255;
    return p;
  };
  unsigned short* xbuf = (unsigned short*)carve((size_t)kN * kH * 2);
  unsigned short* hbuf = (unsigned short*)carve((size_t)kN * kH * 2);
  unsigned short* BtF = (unsigned short*)carve((size_t)kK * kH * 2);
  unsigned short* BtA = (unsigned short*)carve((size_t)kK * kH * 2);
  unsigned short* WtF = (unsigned short*)carve((size_t)kH * 32 * 2);
  unsigned short* WtA = (unsigned short*)carve((size_t)kH * 32 * 2);
  int* cnt = (int*)carve((size_t)kSEG * 4);
  int* offs = (int*)carve((size_t)(kSEG + 1) * 4);
  int* cursor = (int*)carve((size_t)kSEG * 4);
  int* elist = (int*)carve((size_t)kETOT * 4);
  int* bsum = (int*)carve((size_t)kScanBlocks * 4);
  int* bpre = (int*)carve((size_t)kScanBlocks * 4);
  float* invdeg = (float*)carve((size_t)kSEG * 4);
  // adaptive chunk rows (multiple of 64, cap 102400 = full flight set) + 64
  // pad rows for the fragment over-read (GEMM reads rows up to M+62)
  size_t rem = (ws_size > off_b + 4096) ? (ws_size - off_b - 4096) : 0;
  int CH = (int)(rem / ((size_t)kKA * 2)) - 64;
  if (CH > 102400) CH = 102400;
  CH &= ~63;
  if (CH < 64) CH = 64;  // (ws_size too small to function; best effort)
  unsigned short* Achunk = (unsigned short*)carve((size_t)(CH + 64) * kKA * 2);

  // --- encoders (MFMA) ---
  k_build_encWt<<<(2 * kH * 32 + 255) / 256, 256, 0, stream>>>(enc_w_f, enc_w_a,
                                                               WtF, WtA);
  k_enc_mfma<32><<<(kNF + 63) / 64, 256, 0, stream>>>(x_flight, WtF, enc_b_f,
                                                      xbuf, kNF, 0);
  k_enc_mfma<16><<<(kNA + 63) / 64, 256, 0, stream>>>(x_airport, WtA, enc_b_a,
                                                      xbuf, kNA, kNF);

  // --- CSR build ---
  hipMemsetAsync(cnt, 0, (size_t)kSEG * 4, stream);
  const int b0 = 0, b1 = kNA, b2 = kNA + kNF, b3 = kNA + 2 * kNF;
  k_count_all<<<(kETOT + 255) / 256, 256, 0, stream>>>(ei_fa, ei_af, ei_ff,
                                                       ei_aa, cnt);
  k_scan1<<<kScanBlocks, 256, 0, stream>>>(cnt, offs, bsum, invdeg);
  k_scan2<<<1, 256, 0, stream>>>(bsum, bpre);
  k_scan3<<<(kSEG + 255) / 256, 256, 0, stream>>>(offs, cursor, bpre);
  k_fill_all<<<(kETOT + 255) / 256, 256, 0, stream>>>(ei_fa, ei_af, ei_ff,
                                                      ei_aa, cursor, elist);

  // --- layers (ping-pong x buffers) ---
  unsigned short* bufs[2] = {xbuf, hbuf};
  int curb = 0;
  for (int l = 0; l < kL; ++l) {
    const float* comp_l = comp + (size_t)l * 4 * kB;
    const float* basis_l = basis + (size_t)l * kB * kH * kH;
    const float* root_l = root + (size_t)l * kH * kH;
    const float* bias_l = conv_bias + (size_t)l * kH;
    const float* gamma_l = ln_gamma + (size_t)l * kH;
    const float* beta_l = ln_beta + (size_t)l * kH;
    const unsigned short* xc = bufs[curb];
    unsigned short* xn = bufs[curb ^ 1];

    k_build_Bt<<<(2 * kK * kH + 255) / 256, 256, 0, stream>>>(comp_l, basis_l,
                                                              root_l, BtF, BtA);

    // flight rows: slots {r1(af), r2(ff)}, x rows [0, kNF)
    for (int c0 = 0; c0 < kNF; c0 += CH) {
      const int rows = (kNF - c0 < CH) ? (kNF - c0) : CH;
      dim3 gg((rows + 7) / 8, 2);
      k_gather2<<<gg, 256, 0, stream>>>(xc, Achunk, offs, elist, invdeg, b1,
                                        b2, c0, rows);
      dim3 g((rows + 63) / 64);
      k_gemm_fused<<<g, 256, 0, stream>>>(Achunk, xc, xn, BtF, bias_l, gamma_l,
                                          beta_l, rows, c0);
    }
    // airport rows: slots {r0(fa), r3(aa)}, x rows [kNF, kN)
    for (int c0 = 0; c0 < kNA; c0 += CH) {
      const int rows = (kNA - c0 < CH) ? (kNA - c0) : CH;
      dim3 gg((rows + 7) / 8, 2);
      k_gather2<<<gg, 256, 0, stream>>>(xc, Achunk, offs, elist, invdeg, b0,
                                        b3, c0, rows);
      dim3 g((rows + 63) / 64);
      k_gemm_fused<<<g, 256, 0, stream>>>(Achunk, xc, xn, BtA, bias_l, gamma_l,
                                          beta_l, rows, kNF + c0);
    }
    curb ^= 1;
  }

  // --- readout ---
  k_readout<<<(kNF + 3) / 4, 256, 0, stream>>>(bufs[curb], ro_w, ro_b, out);
}

// Round 12
// 1068.408 us; speedup vs baseline: 1.0840x; 1.0840x over previous
//
#include <hip/hip_runtime.h>
#include <cstdint>

// ---------------------------------------------------------------------------
// RGCN (flight/airport heterograph).
// bf16 activation storage; all GEMMs on MFMA (bf16 in, fp32 accum).
// Per layer, per node type, per chunk:
//   Aagg = [agg_relA | agg_relB]  (K=512, bf16)  (gather, chunk-local)
//   acc  = [Aagg | x_cur] @ Bt^T + bias
//          (A & B tiles staged via global_load_lds, TRIPLE-buffered,
//           counted s_waitcnt vmcnt(5) -- loads never drained to 0 in loop)
//   x_nxt = leaky(LN(acc)) + x_cur        (fused epilogue, no h buffer)
// x buffers ping-pong per layer -> gathers always read an immutable x_cur.
// CSR built on-device once per call (count -> scan -> fill).
// ---------------------------------------------------------------------------

namespace {

constexpr int kNF = 100000;
constexpr int kNA = 4000;
constexpr int kN  = 104000;
constexpr int kH  = 256;
constexpr int kL  = 4;
constexpr int kB  = 3;
constexpr int kEFA = 200000;
constexpr int kEAF = 200000;
constexpr int kEFF = 400000;
constexpr int kEAA = 40000;
constexpr int kETOT = 840000;
constexpr int kK = 768;   // logical concat K: 2 agg slots + x
constexpr int kKA = 512;  // Aagg row width
// segment space (concatenated per-relation dst ranges):
// r0 fa->airport [0,kNA) | r1 af->flight [kNA,kNA+kNF)
// r2 ff->flight [kNA+kNF, kNA+2kNF) | r3 aa->airport [kNA+2kNF, kSEG)
constexpr int kSEG = 2 * kNA + 2 * kNF;           // 208000
constexpr int kScanBlocks = (kSEG + 1023) / 1024; // 204

typedef __attribute__((ext_vector_type(8))) short short8v;
typedef __attribute__((ext_vector_type(4))) float float4v;

__device__ __forceinline__ float b2f(unsigned short u) {
  union { unsigned int i; float f; } v;
  v.i = ((unsigned int)u) << 16;
  return v.f;
}
__device__ __forceinline__ unsigned short f2b(float f) {
  union { float f; unsigned int i; } v;
  v.f = f;
  unsigned int x = v.i;
  x += 0x7fffu + ((x >> 16) & 1u);  // round-to-nearest-even
  return (unsigned short)(x >> 16);
}

// async global->LDS, 16 bytes per lane; dst is wave-uniform base, lane i
// lands at dst + i*16.
__device__ __forceinline__ void gload16(const unsigned short* gsrc,
                                        unsigned short* lds) {
  __builtin_amdgcn_global_load_lds(
      (const __attribute__((address_space(1))) unsigned int*)gsrc,
      (__attribute__((address_space(3))) unsigned int*)lds, 16, 0, 0);
}

// ---------------------------------------------------------------------------
// Encoder weight transpose+pad: Wt[n][k] (bf16, k padded to 32)
// ---------------------------------------------------------------------------
__global__ void k_build_encWt(const float* __restrict__ wf,
                              const float* __restrict__ wa,
                              unsigned short* __restrict__ WtF,
                              unsigned short* __restrict__ WtA) {
  const int idx = blockIdx.x * 256 + threadIdx.x;
  if (idx >= 2 * kH * 32) return;
  const int t = idx / (kH * 32);
  const int rem = idx % (kH * 32);
  const int n = rem >> 5;
  const int k = rem & 31;
  if (t == 0) {
    WtF[n * 32 + k] = f2b(wf[k * kH + n]);
  } else {
    WtA[n * 32 + k] = (k < 16) ? f2b(wa[k * kH + n]) : (unsigned short)0;
  }
}

// ---------------------------------------------------------------------------
// MFMA encoder: xout[rowoff+r] = xin[r] @ W + bias  (Wt [256][32] bf16)
// ---------------------------------------------------------------------------
template <int KIN>
__global__ __launch_bounds__(256) void k_enc_mfma(
    const float* __restrict__ xin, const unsigned short* __restrict__ Wt,
    const float* __restrict__ bias, unsigned short* __restrict__ xout, int M,
    int rowoff) {
  __shared__ __align__(16) unsigned short As[64][40];
  const int tid = threadIdx.x;
  const int wave = tid >> 6;
  const int lane = tid & 63;
  const int fr = lane & 15;
  const int fq = lane >> 4;
  const int ncol0 = wave * 64;
  const int brow = blockIdx.x * 64;

  const int row = tid >> 2;
  const int col0 = (tid & 3) * 8;
  float4 f0 = make_float4(0.f, 0.f, 0.f, 0.f);
  float4 f1 = make_float4(0.f, 0.f, 0.f, 0.f);
  if (brow + row < M) {
    if (col0 < KIN) f0 = *(const float4*)&xin[(size_t)(brow + row) * KIN + col0];
    if (col0 + 4 < KIN)
      f1 = *(const float4*)&xin[(size_t)(brow + row) * KIN + col0 + 4];
  }
  uint4 packed;
  packed.x = (unsigned int)f2b(f0.x) | ((unsigned int)f2b(f0.y) << 16);
  packed.y = (unsigned int)f2b(f0.z) | ((unsigned int)f2b(f0.w) << 16);
  packed.z = (unsigned int)f2b(f1.x) | ((unsigned int)f2b(f1.y) << 16);
  packed.w = (unsigned int)f2b(f1.z) | ((unsigned int)f2b(f1.w) << 16);
  *(uint4*)&As[row][col0] = packed;
  __syncthreads();

  short8v bfrag[4];
#pragma unroll
  for (int ni = 0; ni < 4; ++ni)
    bfrag[ni] = *(const short8v*)&Wt[(size_t)(ncol0 + ni * 16 + fr) * 32 + fq * 8];

  float4v acc[4][4];
#pragma unroll
  for (int mi = 0; mi < 4; ++mi) {
    const short8v afrag = *(const short8v*)&As[mi * 16 + fr][fq * 8];
#pragma unroll
    for (int ni = 0; ni < 4; ++ni)
      acc[mi][ni] = __builtin_amdgcn_mfma_f32_16x16x32_bf16(
          afrag, bfrag[ni], (float4v)(0.f), 0, 0, 0);
  }

#pragma unroll
  for (int ni = 0; ni < 4; ++ni) {
    const int col = ncol0 + ni * 16 + fr;
    const float bb = bias[col];
#pragma unroll
    for (int mi = 0; mi < 4; ++mi) {
      const int row0 = brow + mi * 16 + fq * 4;
#pragma unroll
      for (int reg = 0; reg < 4; ++reg) {
        const int r = row0 + reg;
        if (r < M) xout[(size_t)(rowoff + r) * kH + col] = f2b(acc[mi][ni][reg] + bb);
      }
    }
  }
}

// ---------------------------------------------------------------------------
// CSR build (all relations in one dispatch)
// ---------------------------------------------------------------------------
__device__ __forceinline__ void edge_decode(int i, const int* ei_fa,
                                            const int* ei_af, const int* ei_ff,
                                            const int* ei_aa, int& src,
                                            int& dstseg) {
  if (i < kEFA) {
    src = ei_fa[i];
    dstseg = 0 + ei_fa[kEFA + i];
  } else if (i < kEFA + kEAF) {
    const int j = i - kEFA;
    src = kNF + ei_af[j];
    dstseg = kNA + ei_af[kEAF + j];
  } else if (i < kEFA + kEAF + kEFF) {
    const int j = i - kEFA - kEAF;
    src = ei_ff[j];
    dstseg = kNA + kNF + ei_ff[kEFF + j];
  } else {
    const int j = i - kEFA - kEAF - kEFF;
    src = kNF + ei_aa[j];
    dstseg = kNA + 2 * kNF + ei_aa[kEAA + j];
  }
}

__global__ void k_count_all(const int* __restrict__ ei_fa,
                            const int* __restrict__ ei_af,
                            const int* __restrict__ ei_ff,
                            const int* __restrict__ ei_aa,
                            int* __restrict__ cnt) {
  const int i = blockIdx.x * 256 + threadIdx.x;
  if (i >= kETOT) return;
  int src, dstseg;
  edge_decode(i, ei_fa, ei_af, ei_ff, ei_aa, src, dstseg);
  atomicAdd(&cnt[dstseg], 1);
}

__global__ void k_scan1(const int* __restrict__ cnt, int* __restrict__ out,
                        int* __restrict__ bsum, float* __restrict__ invdeg) {
  __shared__ int sh[256];
  const int tid = threadIdx.x;
  const int base = blockIdx.x * 1024 + tid * 4;
  int v[4];
#pragma unroll
  for (int j = 0; j < 4; ++j) v[j] = (base + j < kSEG) ? cnt[base + j] : 0;
#pragma unroll
  for (int j = 0; j < 4; ++j)
    if (base + j < kSEG)
      invdeg[base + j] = 1.0f / (float)(v[j] > 0 ? v[j] : 1);
  const int tsum = v[0] + v[1] + v[2] + v[3];
  sh[tid] = tsum;
  __syncthreads();
  for (int o = 1; o < 256; o <<= 1) {
    int t = (tid >= o) ? sh[tid - o] : 0;
    __syncthreads();
    sh[tid] += t;
    __syncthreads();
  }
  const int excl = sh[tid] - tsum;
  int run = excl;
#pragma unroll
  for (int j = 0; j < 4; ++j) {
    if (base + j < kSEG) out[base + j] = run;
    run += v[j];
  }
  if (tid == 255) bsum[blockIdx.x] = sh[255];
}

__global__ void k_scan2(const int* __restrict__ bsum, int* __restrict__ bpre) {
  __shared__ int sh[256];
  const int tid = threadIdx.x;
  const int v = (tid < kScanBlocks) ? bsum[tid] : 0;
  sh[tid] = v;
  __syncthreads();
  for (int o = 1; o < 256; o <<= 1) {
    int t = (tid >= o) ? sh[tid - o] : 0;
    __syncthreads();
    sh[tid] += t;
    __syncthreads();
  }
  if (tid < kScanBlocks) bpre[tid] = sh[tid] - v;
}

__global__ void k_scan3(int* __restrict__ off, int* __restrict__ cursor,
                        const int* __restrict__ bpre) {
  const int i = blockIdx.x * 256 + threadIdx.x;
  if (i < kSEG) {
    const int val = off[i] + bpre[i >> 10];
    off[i] = val;
    cursor[i] = val;
  }
  if (i == 0) off[kSEG] = kETOT;
}

__global__ void k_fill_all(const int* __restrict__ ei_fa,
                           const int* __restrict__ ei_af,
                           const int* __restrict__ ei_ff,
                           const int* __restrict__ ei_aa,
                           int* __restrict__ cursor, int* __restrict__ elist) {
  const int i = blockIdx.x * 256 + threadIdx.x;
  if (i >= kETOT) return;
  int src, dstseg;
  edge_decode(i, ei_fa, ei_af, ei_ff, ei_aa, src, dstseg);
  const int pos = atomicAdd(&cursor[dstseg], 1);
  elist[pos] = src;
}

// ---------------------------------------------------------------------------
// Stacked transposed B build (bf16):
//   BtF[n][k] = ([W_r1; W_r2; root])[k][n],  BtA likewise with {r0, r3}.
// ---------------------------------------------------------------------------
__global__ void k_build_Bt(const float* __restrict__ comp_l,
                           const float* __restrict__ basis_l,
                           const float* __restrict__ root_l,
                           unsigned short* __restrict__ BtF,
                           unsigned short* __restrict__ BtA) {
  const int idx = blockIdx.x * 256 + threadIdx.x;
  if (idx >= 2 * kK * kH) return;
  const int t = idx / (kK * kH);
  const int rem = idx % (kK * kH);
  const int n = rem / kK;     // 0..255 output col
  const int k = rem % kK;     // 0..767
  const int slot = k >> 8;    // 0,1,2
  const int wrow = k & 255;
  float val;
  if (slot == 2) {
    val = root_l[wrow * kH + n];
  } else {
    const int r = (t == 0) ? (slot == 0 ? 1 : 2) : (slot == 0 ? 0 : 3);
    const int io = wrow * kH + n;
    val = comp_l[r * kB + 0] * basis_l[0 * kH * kH + io] +
          comp_l[r * kB + 1] * basis_l[1 * kH * kH + io] +
          comp_l[r * kB + 2] * basis_l[2 * kH * kH + io];
  }
  (t == 0 ? BtF : BtA)[(size_t)n * kK + k] = f2b(val);
}

// ---------------------------------------------------------------------------
// Gather-mean: Aagg[d][slot*256..] = mean_{src in CSR[d]} x[src]  (bf16)
// 32 lanes per destination (2 dsts per wave); blockIdx.y = slot (0/1).
// ---------------------------------------------------------------------------
__global__ __launch_bounds__(256) void k_gather2(
    const unsigned short* __restrict__ x, unsigned short* __restrict__ Aagg,
    const int* __restrict__ off, const int* __restrict__ elist,
    const float* __restrict__ invdeg, int segbase0, int segbase1, int c0,
    int nrows) {
  const int half = threadIdx.x >> 5;  // 0..7
  const int lane = threadIdx.x & 31;
  const int d = blockIdx.x * 8 + half;
  const int slot = blockIdx.y;
  if (d >= nrows) return;
  const int s = (slot == 0 ? segbase0 : segbase1) + c0 + d;
  const int lo = off[s], hi = off[s + 1];
  const float iv = invdeg[s];
  float a0 = 0.f, a1 = 0.f, a2 = 0.f, a3 = 0.f;
  float a4 = 0.f, a5 = 0.f, a6 = 0.f, a7 = 0.f;
  const unsigned short* xl = x + lane * 8;
  int e = lo;
  for (; e + 3 < hi; e += 4) {
    const int s0 = elist[e], s1 = elist[e + 1];
    const int s2 = elist[e + 2], s3 = elist[e + 3];
    const uint4 v0 = *(const uint4*)(xl + (size_t)s0 * kH);
    const uint4 v1 = *(const uint4*)(xl + (size_t)s1 * kH);
    const uint4 v2 = *(const uint4*)(xl + (size_t)s2 * kH);
    const uint4 v3 = *(const uint4*)(xl + (size_t)s3 * kH);
    a0 += b2f((unsigned short)v0.x) + b2f((unsigned short)v1.x) +
          b2f((unsigned short)v2.x) + b2f((unsigned short)v3.x);
    a1 += b2f((unsigned short)(v0.x >> 16)) + b2f((unsigned short)(v1.x >> 16)) +
          b2f((unsigned short)(v2.x >> 16)) + b2f((unsigned short)(v3.x >> 16));
    a2 += b2f((unsigned short)v0.y) + b2f((unsigned short)v1.y) +
          b2f((unsigned short)v2.y) + b2f((unsigned short)v3.y);
    a3 += b2f((unsigned short)(v0.y >> 16)) + b2f((unsigned short)(v1.y >> 16)) +
          b2f((unsigned short)(v2.y >> 16)) + b2f((unsigned short)(v3.y >> 16));
    a4 += b2f((unsigned short)v0.z) + b2f((unsigned short)v1.z) +
          b2f((unsigned short)v2.z) + b2f((unsigned short)v3.z);
    a5 += b2f((unsigned short)(v0.z >> 16)) + b2f((unsigned short)(v1.z >> 16)) +
          b2f((unsigned short)(v2.z >> 16)) + b2f((unsigned short)(v3.z >> 16));
    a6 += b2f((unsigned short)v0.w) + b2f((unsigned short)v1.w) +
          b2f((unsigned short)v2.w) + b2f((unsigned short)v3.w);
    a7 += b2f((unsigned short)(v0.w >> 16)) + b2f((unsigned short)(v1.w >> 16)) +
          b2f((unsigned short)(v2.w >> 16)) + b2f((unsigned short)(v3.w >> 16));
  }
  for (; e < hi; ++e) {
    const int s0 = elist[e];
    const uint4 v0 = *(const uint4*)(xl + (size_t)s0 * kH);
    a0 += b2f((unsigned short)v0.x);
    a1 += b2f((unsigned short)(v0.x >> 16));
    a2 += b2f((unsigned short)v0.y);
    a3 += b2f((unsigned short)(v0.y >> 16));
    a4 += b2f((unsigned short)v0.z);
    a5 += b2f((unsigned short)(v0.z >> 16));
    a6 += b2f((unsigned short)v0.w);
    a7 += b2f((unsigned short)(v0.w >> 16));
  }
  uint4 o;
  o.x = (unsigned int)f2b(a0 * iv) | ((unsigned int)f2b(a1 * iv) << 16);
  o.y = (unsigned int)f2b(a2 * iv) | ((unsigned int)f2b(a3 * iv) << 16);
  o.z = (unsigned int)f2b(a4 * iv) | ((unsigned int)f2b(a5 * iv) << 16);
  o.w = (unsigned int)f2b(a6 * iv) | ((unsigned int)f2b(a7 * iv) << 16);
  *(uint4*)&Aagg[(size_t)d * kKA + slot * kH + lane * 8] = o;
}

// ---------------------------------------------------------------------------
// Fused MFMA GEMM + LayerNorm + leaky + residual.
//   acc = [Aagg | xcur] @ Bt^T + bias   (K=768, BK=32, 24 K-tiles)
// A [64][32] and B [256][32] tiles staged via global_load_lds, TRIPLE
// buffered; stage issued 2 tiles ahead; per-iter counted s_waitcnt vmcnt(5)
// (tile t+1 complete, t+2 in flight) + raw s_barrier -- the in-flight loads
// are never drained to 0 inside the main loop (T3/T4).
// Race audit: buffer (t+2)%3 == (t-1)%3; its last reads were in iter t-1
// before that iter's lgkmcnt(0)+barrier, so write-after-read is safe.
// Block: 256 thr (4 waves), tile 64 rows x 256 cols (wave w: cols w*64).
// ---------------------------------------------------------------------------
__global__ __launch_bounds__(256) void k_gemm_fused(
    const unsigned short* __restrict__ Aagg,
    const unsigned short* __restrict__ xcur, unsigned short* __restrict__ xnxt,
    const unsigned short* __restrict__ Bt, const float* __restrict__ bias,
    const float* __restrict__ gamma, const float* __restrict__ beta, int M,
    int grow0) {
  __shared__ __align__(16) unsigned short As[3][64][32];
  __shared__ __align__(16) unsigned short Bs[3][256][32];
  __shared__ float redS[4][64];
  __shared__ float redQ[4][64];
  __shared__ float stat[64][2];

  const int tid = threadIdx.x;
  const int wave = tid >> 6;
  const int lane = tid & 63;
  const int fr = lane & 15;
  const int fq = lane >> 4;
  const int ncol0 = wave * 64;
  const int brow = blockIdx.x * 64;

  // staging lane decomposition: 4 lanes per row (16B granules), 16 rows/instr
  const int srow = lane >> 2;                    // 0..15
  const int sg = (lane & 3) ^ (srow & 3);        // swizzled source granule
  const int arow = wave * 16 + srow;             // A: wave w stages rows w*16..
  const unsigned short* Asrc_agg = Aagg + (size_t)(brow + arow) * kKA + sg * 8;
  const unsigned short* Asrc_x =
      xcur + (size_t)(grow0 + brow + arow) * kH + sg * 8;
  const unsigned short* Bsrc = Bt + (size_t)(wave * 64 + srow) * kK + sg * 8;

#define STAGE(buf, t)                                                         \
  do {                                                                        \
    const int kb_ = (t) * 32;                                                 \
    gload16((kb_ < kKA) ? (Asrc_agg + kb_) : (Asrc_x + (kb_ - kKA)),          \
            &As[buf][wave * 16][0]);                                          \
    _Pragma("unroll") for (int j_ = 0; j_ < 4; ++j_)                          \
        gload16(Bsrc + (size_t)(j_ * 16) * kK + kb_,                          \
                &Bs[buf][wave * 64 + j_ * 16][0]);                            \
  } while (0)

  float4v acc[4][4];
#pragma unroll
  for (int mi = 0; mi < 4; ++mi)
#pragma unroll
    for (int ni = 0; ni < 4; ++ni) acc[mi][ni] = (float4v)(0.f);

  const int rg = (fr & 3);  // read-side swizzle component

  // prologue: stage tiles 0 and 1; wait tile 0 (leave tile 1 in flight)
  STAGE(0, 0);
  STAGE(1, 1);
  asm volatile("s_waitcnt vmcnt(5)" ::: "memory");
  asm volatile("s_barrier" ::: "memory");

  for (int t = 0; t < 24; ++t) {
    const int cur = t % 3;
    // 1. read this tile's fragments into registers (completes before STAGE)
    short8v afrag[4], bfrag[4];
#pragma unroll
    for (int mi = 0; mi < 4; ++mi)
      afrag[mi] = *(const short8v*)&As[cur][mi * 16 + fr][(fq ^ rg) * 8];
#pragma unroll
    for (int ni = 0; ni < 4; ++ni)
      bfrag[ni] =
          *(const short8v*)&Bs[cur][ncol0 + ni * 16 + fr][(fq ^ rg) * 8];
    asm volatile("s_waitcnt lgkmcnt(0)" ::: "memory");
    // 2. issue stage for tile t+2 (overwrites buf (t-1)%3 -- safe, see audit)
    if (t < 22) STAGE((t + 2) % 3, t + 2);
    // 3. compute (reg-only; loads for t+1/t+2 fly underneath)
#pragma unroll
    for (int mi = 0; mi < 4; ++mi)
#pragma unroll
      for (int ni = 0; ni < 4; ++ni)
        acc[mi][ni] = __builtin_amdgcn_mfma_f32_16x16x32_bf16(
            afrag[mi], bfrag[ni], acc[mi][ni], 0, 0, 0);
    // 4. counted wait: tile t+1 landed, tile t+2 still in flight
    if (t < 22) {
      asm volatile("s_waitcnt vmcnt(5)" ::: "memory");
    } else {
      asm volatile("s_waitcnt vmcnt(0)" ::: "memory");
    }
    asm volatile("s_barrier" ::: "memory");
  }
#undef STAGE

  // ---- fused epilogue: bias, LN stats, leaky, residual, bf16 store ----
  float bb[4], gam[4], bet[4];
#pragma unroll
  for (int ni = 0; ni < 4; ++ni) {
    const int col = ncol0 + ni * 16 + fr;
    bb[ni] = bias[col];
    gam[ni] = gamma[col];
    bet[ni] = beta[col];
  }
#pragma unroll
  for (int mi = 0; mi < 4; ++mi)
#pragma unroll
    for (int ni = 0; ni < 4; ++ni)
#pragma unroll
      for (int reg = 0; reg < 4; ++reg) acc[mi][ni][reg] += bb[ni];

#pragma unroll
  for (int mi = 0; mi < 4; ++mi) {
#pragma unroll
    for (int reg = 0; reg < 4; ++reg) {
      float s = 0.f, q = 0.f;
#pragma unroll
      for (int ni = 0; ni < 4; ++ni) {
        const float v = acc[mi][ni][reg];
        s += v;
        q += v * v;
      }
#pragma unroll
      for (int o = 1; o < 16; o <<= 1) {
        s += __shfl_xor(s, o);
        q += __shfl_xor(q, o);
      }
      if (fr == 0) {
        const int rl = mi * 16 + fq * 4 + reg;
        redS[wave][rl] = s;
        redQ[wave][rl] = q;
      }
    }
  }
  __syncthreads();
  if (tid < 64) {
    const float s = redS[0][tid] + redS[1][tid] + redS[2][tid] + redS[3][tid];
    const float q = redQ[0][tid] + redQ[1][tid] + redQ[2][tid] + redQ[3][tid];
    const float mu = s * (1.f / kH);
    const float var = q * (1.f / kH) - mu * mu;
    stat[tid][0] = mu;
    stat[tid][1] = rsqrtf(var + 1e-5f);
  }
  __syncthreads();

#pragma unroll
  for (int mi = 0; mi < 4; ++mi) {
#pragma unroll
    for (int reg = 0; reg < 4; ++reg) {
      const int rl = mi * 16 + fq * 4 + reg;
      const int r = brow + rl;
      if (r >= M) continue;
      const float mu = stat[rl][0];
      const float rs = stat[rl][1];
      const size_t gr = (size_t)(grow0 + r) * kH;
#pragma unroll
      for (int ni = 0; ni < 4; ++ni) {
        const int col = ncol0 + ni * 16 + fr;
        float t = (acc[mi][ni][reg] - mu) * rs * gam[ni] + bet[ni];
        t = t > 0.f ? t : 0.1f * t;
        const float xo = b2f(xcur[gr + col]);
        xnxt[gr + col] = f2b(xo + t);
      }
    }
  }
}

// ---------------------------------------------------------------------------
// Readout: out[n] = dot(x[n], ro_w) + ro_b  (flight rows), fp32 out.
// ---------------------------------------------------------------------------
__global__ __launch_bounds__(256) void k_readout(
    const unsigned short* __restrict__ x, const float* __restrict__ w,
    const float* __restrict__ b, float* __restrict__ out) {
  const int wave = threadIdx.x >> 6;
  const int lane = threadIdx.x & 63;
  const int row = blockIdx.x * 4 + wave;
  if (row >= kNF) return;
  const ushort4 v = *(const ushort4*)&x[(size_t)row * kH + (lane << 2)];
  const float4 wv = *(const float4*)&w[lane << 2];
  float s = b2f(v.x) * wv.x + b2f(v.y) * wv.y + b2f(v.z) * wv.z +
            b2f(v.w) * wv.w;
#pragma unroll
  for (int o = 1; o < 64; o <<= 1) s += __shfl_xor(s, o);
  if (lane == 0) out[row] = s + b[0];
}

}  // namespace

// ---------------------------------------------------------------------------
extern "C" void kernel_launch(void* const* d_in, const int* in_sizes, int n_in,
                              void* d_out, int out_size, void* d_ws,
                              size_t ws_size, hipStream_t stream) {
  const float* x_flight = (const float*)d_in[0];
  const float* x_airport = (const float*)d_in[1];
  const float* enc_w_f = (const float*)d_in[2];
  const float* enc_b_f = (const float*)d_in[3];
  const float* enc_w_a = (const float*)d_in[4];
  const float* enc_b_a = (const float*)d_in[5];
  const float* basis = (const float*)d_in[6];
  const float* comp = (const float*)d_in[7];
  const float* root = (const float*)d_in[8];
  const float* conv_bias = (const float*)d_in[9];
  const float* ln_gamma = (const float*)d_in[10];
  const float* ln_beta = (const float*)d_in[11];
  const float* ro_w = (const float*)d_in[12];
  const float* ro_b = (const float*)d_in[13];
  const int* ei_fa = (const int*)d_in[14];
  const int* ei_af = (const int*)d_in[15];
  const int* ei_ff = (const int*)d_in[16];
  const int* ei_aa = (const int*)d_in[17];
  float* out = (float*)d_out;

  // workspace carve (fixed buffers first, then adaptive A-chunk)
  char* base = (char*)d_ws;
  size_t off_b = 0;
  auto carve = [&](size_t bytes) -> char* {
    char* p = base + off_b;
    off_b += (bytes + 255) & ~(size_t)255;
    return p;
  };
  unsigned short* xbuf = (unsigned short*)carve((size_t)kN * kH * 2);
  unsigned short* hbuf = (unsigned short*)carve((size_t)kN * kH * 2);
  unsigned short* BtF = (unsigned short*)carve((size_t)kK * kH * 2);
  unsigned short* BtA = (unsigned short*)carve((size_t)kK * kH * 2);
  unsigned short* WtF = (unsigned short*)carve((size_t)kH * 32 * 2);
  unsigned short* WtA = (unsigned short*)carve((size_t)kH * 32 * 2);
  int* cnt = (int*)carve((size_t)kSEG * 4);
  int* offs = (int*)carve((size_t)(kSEG + 1) * 4);
  int* cursor = (int*)carve((size_t)kSEG * 4);
  int* elist = (int*)carve((size_t)kETOT * 4);
  int* bsum = (int*)carve((size_t)kScanBlocks * 4);
  int* bpre = (int*)carve((size_t)kScanBlocks * 4);
  float* invdeg = (float*)carve((size_t)kSEG * 4);
  // adaptive chunk rows (multiple of 64, cap 102400 = full flight set) + 64
  // pad rows for the fragment over-read (GEMM reads rows up to M+62)
  size_t rem = (ws_size > off_b + 4096) ? (ws_size - off_b - 4096) : 0;
  int CH = (int)(rem / ((size_t)kKA * 2)) - 64;
  if (CH > 102400) CH = 102400;
  CH &= ~63;
  if (CH < 64) CH = 64;  // (ws_size too small to function; best effort)
  unsigned short* Achunk = (unsigned short*)carve((size_t)(CH + 64) * kKA * 2);

  // --- encoders (MFMA) ---
  k_build_encWt<<<(2 * kH * 32 + 255) / 256, 256, 0, stream>>>(enc_w_f, enc_w_a,
                                                               WtF, WtA);
  k_enc_mfma<32><<<(kNF + 63) / 64, 256, 0, stream>>>(x_flight, WtF, enc_b_f,
                                                      xbuf, kNF, 0);
  k_enc_mfma<16><<<(kNA + 63) / 64, 256, 0, stream>>>(x_airport, WtA, enc_b_a,
                                                      xbuf, kNA, kNF);

  // --- CSR build ---
  hipMemsetAsync(cnt, 0, (size_t)kSEG * 4, stream);
  const int b0 = 0, b1 = kNA, b2 = kNA + kNF, b3 = kNA + 2 * kNF;
  k_count_all<<<(kETOT + 255) / 256, 256, 0, stream>>>(ei_fa, ei_af, ei_ff,
                                                       ei_aa, cnt);
  k_scan1<<<kScanBlocks, 256, 0, stream>>>(cnt, offs, bsum, invdeg);
  k_scan2<<<1, 256, 0, stream>>>(bsum, bpre);
  k_scan3<<<(kSEG + 255) / 256, 256, 0, stream>>>(offs, cursor, bpre);
  k_fill_all<<<(kETOT + 255) / 256, 256, 0, stream>>>(ei_fa, ei_af, ei_ff,
                                                      ei_aa, cursor, elist);

  // --- layers (ping-pong x buffers) ---
  unsigned short* bufs[2] = {xbuf, hbuf};
  int curb = 0;
  for (int l = 0; l < kL; ++l) {
    const float* comp_l = comp + (size_t)l * 4 * kB;
    const float* basis_l = basis + (size_t)l * kB * kH * kH;
    const float* root_l = root + (size_t)l * kH * kH;
    const float* bias_l = conv_bias + (size_t)l * kH;
    const float* gamma_l = ln_gamma + (size_t)l * kH;
    const float* beta_l = ln_beta + (size_t)l * kH;
    const unsigned short* xc = bufs[curb];
    unsigned short* xn = bufs[curb ^ 1];

    k_build_Bt<<<(2 * kK * kH + 255) / 256, 256, 0, stream>>>(comp_l, basis_l,
                                                              root_l, BtF, BtA);

    // flight rows: slots {r1(af), r2(ff)}, x rows [0, kNF)
    for (int c0 = 0; c0 < kNF; c0 += CH) {
      const int rows = (kNF - c0 < CH) ? (kNF - c0) : CH;
      dim3 gg((rows + 7) / 8, 2);
      k_gather2<<<gg, 256, 0, stream>>>(xc, Achunk, offs, elist, invdeg, b1,
                                        b2, c0, rows);
      dim3 g((rows + 63) / 64);
      k_gemm_fused<<<g, 256, 0, stream>>>(Achunk, xc, xn, BtF, bias_l, gamma_l,
                                          beta_l, rows, c0);
    }
    // airport rows: slots {r0(fa), r3(aa)}, x rows [kNF, kN)
    for (int c0 = 0; c0 < kNA; c0 += CH) {
      const int rows = (kNA - c0 < CH) ? (kNA - c0) : CH;
      dim3 gg((rows + 7) / 8, 2);
      k_gather2<<<gg, 256, 0, stream>>>(xc, Achunk, offs, elist, invdeg, b0,
                                        b3, c0, rows);
      dim3 g((rows + 63) / 64);
      k_gemm_fused<<<g, 256, 0, stream>>>(Achunk, xc, xn, BtA, bias_l, gamma_l,
                                          beta_l, rows, kNF + c0);
    }
    curb ^= 1;
  }

  // --- readout ---
  k_readout<<<(kNF + 3) / 4, 256, 0, stream>>>(bufs[curb], ro_w, ro_b, out);
}

// Round 13
// 1061.358 us; speedup vs baseline: 1.0912x; 1.0066x over previous
//
#include <hip/hip_runtime.h>
#include <cstdint>

// ---------------------------------------------------------------------------
// RGCN (flight/airport heterograph).
// bf16 activation storage; all GEMMs on MFMA (bf16 in, fp32 accum).
// Per layer, per node type, per chunk:
//   Aagg = [agg_relA | agg_relB]  (K=512, bf16)  (gather, chunk-local)
//   acc  = [Aagg | x_cur] @ Bt^T + bias
//          (A & B tiles via global_load_lds, TRIPLE-buffered, counted vmcnt;
//           512 threads / 8 waves -> 4 waves/SIMD for stall overlap)
//   x_nxt = leaky(LN(acc)) + x_cur        (fused epilogue, no h buffer)
// x buffers ping-pong per layer -> gathers always read an immutable x_cur.
// CSR built on-device once per call (count -> scan -> fill).
// ---------------------------------------------------------------------------

namespace {

constexpr int kNF = 100000;
constexpr int kNA = 4000;
constexpr int kN  = 104000;
constexpr int kH  = 256;
constexpr int kL  = 4;
constexpr int kB  = 3;
constexpr int kEFA = 200000;
constexpr int kEAF = 200000;
constexpr int kEFF = 400000;
constexpr int kEAA = 40000;
constexpr int kETOT = 840000;
constexpr int kK = 768;   // logical concat K: 2 agg slots + x
constexpr int kKA = 512;  // Aagg row width
// segment space (concatenated per-relation dst ranges):
// r0 fa->airport [0,kNA) | r1 af->flight [kNA,kNA+kNF)
// r2 ff->flight [kNA+kNF, kNA+2kNF) | r3 aa->airport [kNA+2kNF, kSEG)
constexpr int kSEG = 2 * kNA + 2 * kNF;           // 208000
constexpr int kScanBlocks = (kSEG + 1023) / 1024; // 204

typedef __attribute__((ext_vector_type(8))) short short8v;
typedef __attribute__((ext_vector_type(4))) float float4v;

__device__ __forceinline__ float b2f(unsigned short u) {
  union { unsigned int i; float f; } v;
  v.i = ((unsigned int)u) << 16;
  return v.f;
}
__device__ __forceinline__ unsigned short f2b(float f) {
  union { float f; unsigned int i; } v;
  v.f = f;
  unsigned int x = v.i;
  x += 0x7fffu + ((x >> 16) & 1u);  // round-to-nearest-even
  return (unsigned short)(x >> 16);
}

// async global->LDS, 16 bytes per lane; dst is wave-uniform base, lane i
// lands at dst + i*16.
__device__ __forceinline__ void gload16(const unsigned short* gsrc,
                                        unsigned short* lds) {
  __builtin_amdgcn_global_load_lds(
      (const __attribute__((address_space(1))) unsigned int*)gsrc,
      (__attribute__((address_space(3))) unsigned int*)lds, 16, 0, 0);
}

// bank swizzle for 16-row x 32-ushort tiles: rows r, r+4, r+8, r+12 get
// distinct granule rotations (old r&3 collided on them).
__device__ __forceinline__ int swz16(int r) {
  return (r & 3) ^ ((r >> 2) & 3);
}

// ---------------------------------------------------------------------------
// Encoder weight transpose+pad: Wt[n][k] (bf16, k padded to 32)
// ---------------------------------------------------------------------------
__global__ void k_build_encWt(const float* __restrict__ wf,
                              const float* __restrict__ wa,
                              unsigned short* __restrict__ WtF,
                              unsigned short* __restrict__ WtA) {
  const int idx = blockIdx.x * 256 + threadIdx.x;
  if (idx >= 2 * kH * 32) return;
  const int t = idx / (kH * 32);
  const int rem = idx % (kH * 32);
  const int n = rem >> 5;
  const int k = rem & 31;
  if (t == 0) {
    WtF[n * 32 + k] = f2b(wf[k * kH + n]);
  } else {
    WtA[n * 32 + k] = (k < 16) ? f2b(wa[k * kH + n]) : (unsigned short)0;
  }
}

// ---------------------------------------------------------------------------
// MFMA encoder: xout[rowoff+r] = xin[r] @ W + bias  (Wt [256][32] bf16)
// ---------------------------------------------------------------------------
template <int KIN>
__global__ __launch_bounds__(256) void k_enc_mfma(
    const float* __restrict__ xin, const unsigned short* __restrict__ Wt,
    const float* __restrict__ bias, unsigned short* __restrict__ xout, int M,
    int rowoff) {
  __shared__ __align__(16) unsigned short As[64][40];
  const int tid = threadIdx.x;
  const int wave = tid >> 6;
  const int lane = tid & 63;
  const int fr = lane & 15;
  const int fq = lane >> 4;
  const int ncol0 = wave * 64;
  const int brow = blockIdx.x * 64;

  const int row = tid >> 2;
  const int col0 = (tid & 3) * 8;
  float4 f0 = make_float4(0.f, 0.f, 0.f, 0.f);
  float4 f1 = make_float4(0.f, 0.f, 0.f, 0.f);
  if (brow + row < M) {
    if (col0 < KIN) f0 = *(const float4*)&xin[(size_t)(brow + row) * KIN + col0];
    if (col0 + 4 < KIN)
      f1 = *(const float4*)&xin[(size_t)(brow + row) * KIN + col0 + 4];
  }
  uint4 packed;
  packed.x = (unsigned int)f2b(f0.x) | ((unsigned int)f2b(f0.y) << 16);
  packed.y = (unsigned int)f2b(f0.z) | ((unsigned int)f2b(f0.w) << 16);
  packed.z = (unsigned int)f2b(f1.x) | ((unsigned int)f2b(f1.y) << 16);
  packed.w = (unsigned int)f2b(f1.z) | ((unsigned int)f2b(f1.w) << 16);
  *(uint4*)&As[row][col0] = packed;
  __syncthreads();

  short8v bfrag[4];
#pragma unroll
  for (int ni = 0; ni < 4; ++ni)
    bfrag[ni] = *(const short8v*)&Wt[(size_t)(ncol0 + ni * 16 + fr) * 32 + fq * 8];

  float4v acc[4][4];
#pragma unroll
  for (int mi = 0; mi < 4; ++mi) {
    const short8v afrag = *(const short8v*)&As[mi * 16 + fr][fq * 8];
#pragma unroll
    for (int ni = 0; ni < 4; ++ni)
      acc[mi][ni] = __builtin_amdgcn_mfma_f32_16x16x32_bf16(
          afrag, bfrag[ni], (float4v)(0.f), 0, 0, 0);
  }

#pragma unroll
  for (int ni = 0; ni < 4; ++ni) {
    const int col = ncol0 + ni * 16 + fr;
    const float bb = bias[col];
#pragma unroll
    for (int mi = 0; mi < 4; ++mi) {
      const int row0 = brow + mi * 16 + fq * 4;
#pragma unroll
      for (int reg = 0; reg < 4; ++reg) {
        const int r = row0 + reg;
        if (r < M) xout[(size_t)(rowoff + r) * kH + col] = f2b(acc[mi][ni][reg] + bb);
      }
    }
  }
}

// ---------------------------------------------------------------------------
// CSR build (all relations in one dispatch)
// ---------------------------------------------------------------------------
__device__ __forceinline__ void edge_decode(int i, const int* ei_fa,
                                            const int* ei_af, const int* ei_ff,
                                            const int* ei_aa, int& src,
                                            int& dstseg) {
  if (i < kEFA) {
    src = ei_fa[i];
    dstseg = 0 + ei_fa[kEFA + i];
  } else if (i < kEFA + kEAF) {
    const int j = i - kEFA;
    src = kNF + ei_af[j];
    dstseg = kNA + ei_af[kEAF + j];
  } else if (i < kEFA + kEAF + kEFF) {
    const int j = i - kEFA - kEAF;
    src = ei_ff[j];
    dstseg = kNA + kNF + ei_ff[kEFF + j];
  } else {
    const int j = i - kEFA - kEAF - kEFF;
    src = kNF + ei_aa[j];
    dstseg = kNA + 2 * kNF + ei_aa[kEAA + j];
  }
}

__global__ void k_count_all(const int* __restrict__ ei_fa,
                            const int* __restrict__ ei_af,
                            const int* __restrict__ ei_ff,
                            const int* __restrict__ ei_aa,
                            int* __restrict__ cnt) {
  const int i = blockIdx.x * 256 + threadIdx.x;
  if (i >= kETOT) return;
  int src, dstseg;
  edge_decode(i, ei_fa, ei_af, ei_ff, ei_aa, src, dstseg);
  atomicAdd(&cnt[dstseg], 1);
}

__global__ void k_scan1(const int* __restrict__ cnt, int* __restrict__ out,
                        int* __restrict__ bsum, float* __restrict__ invdeg) {
  __shared__ int sh[256];
  const int tid = threadIdx.x;
  const int base = blockIdx.x * 1024 + tid * 4;
  int v[4];
#pragma unroll
  for (int j = 0; j < 4; ++j) v[j] = (base + j < kSEG) ? cnt[base + j] : 0;
#pragma unroll
  for (int j = 0; j < 4; ++j)
    if (base + j < kSEG)
      invdeg[base + j] = 1.0f / (float)(v[j] > 0 ? v[j] : 1);
  const int tsum = v[0] + v[1] + v[2] + v[3];
  sh[tid] = tsum;
  __syncthreads();
  for (int o = 1; o < 256; o <<= 1) {
    int t = (tid >= o) ? sh[tid - o] : 0;
    __syncthreads();
    sh[tid] += t;
    __syncthreads();
  }
  const int excl = sh[tid] - tsum;
  int run = excl;
#pragma unroll
  for (int j = 0; j < 4; ++j) {
    if (base + j < kSEG) out[base + j] = run;
    run += v[j];
  }
  if (tid == 255) bsum[blockIdx.x] = sh[255];
}

__global__ void k_scan2(const int* __restrict__ bsum, int* __restrict__ bpre) {
  __shared__ int sh[256];
  const int tid = threadIdx.x;
  const int v = (tid < kScanBlocks) ? bsum[tid] : 0;
  sh[tid] = v;
  __syncthreads();
  for (int o = 1; o < 256; o <<= 1) {
    int t = (tid >= o) ? sh[tid - o] : 0;
    __syncthreads();
    sh[tid] += t;
    __syncthreads();
  }
  if (tid < kScanBlocks) bpre[tid] = sh[tid] - v;
}

__global__ void k_scan3(int* __restrict__ off, int* __restrict__ cursor,
                        const int* __restrict__ bpre) {
  const int i = blockIdx.x * 256 + threadIdx.x;
  if (i < kSEG) {
    const int val = off[i] + bpre[i >> 10];
    off[i] = val;
    cursor[i] = val;
  }
  if (i == 0) off[kSEG] = kETOT;
}

__global__ void k_fill_all(const int* __restrict__ ei_fa,
                           const int* __restrict__ ei_af,
                           const int* __restrict__ ei_ff,
                           const int* __restrict__ ei_aa,
                           int* __restrict__ cursor, int* __restrict__ elist) {
  const int i = blockIdx.x * 256 + threadIdx.x;
  if (i >= kETOT) return;
  int src, dstseg;
  edge_decode(i, ei_fa, ei_af, ei_ff, ei_aa, src, dstseg);
  const int pos = atomicAdd(&cursor[dstseg], 1);
  elist[pos] = src;
}

// ---------------------------------------------------------------------------
// Stacked transposed B build (bf16):
//   BtF[n][k] = ([W_r1; W_r2; root])[k][n],  BtA likewise with {r0, r3}.
// ---------------------------------------------------------------------------
__global__ void k_build_Bt(const float* __restrict__ comp_l,
                           const float* __restrict__ basis_l,
                           const float* __restrict__ root_l,
                           unsigned short* __restrict__ BtF,
                           unsigned short* __restrict__ BtA) {
  const int idx = blockIdx.x * 256 + threadIdx.x;
  if (idx >= 2 * kK * kH) return;
  const int t = idx / (kK * kH);
  const int rem = idx % (kK * kH);
  const int n = rem / kK;     // 0..255 output col
  const int k = rem % kK;     // 0..767
  const int slot = k >> 8;    // 0,1,2
  const int wrow = k & 255;
  float val;
  if (slot == 2) {
    val = root_l[wrow * kH + n];
  } else {
    const int r = (t == 0) ? (slot == 0 ? 1 : 2) : (slot == 0 ? 0 : 3);
    const int io = wrow * kH + n;
    val = comp_l[r * kB + 0] * basis_l[0 * kH * kH + io] +
          comp_l[r * kB + 1] * basis_l[1 * kH * kH + io] +
          comp_l[r * kB + 2] * basis_l[2 * kH * kH + io];
  }
  (t == 0 ? BtF : BtA)[(size_t)n * kK + k] = f2b(val);
}

// ---------------------------------------------------------------------------
// Gather-mean: Aagg[d][slot*256..] = mean_{src in CSR[d]} x[src]  (bf16)
// 32 lanes per destination (2 dsts per wave); blockIdx.y = slot (0/1).
// ---------------------------------------------------------------------------
__global__ __launch_bounds__(256) void k_gather2(
    const unsigned short* __restrict__ x, unsigned short* __restrict__ Aagg,
    const int* __restrict__ off, const int* __restrict__ elist,
    const float* __restrict__ invdeg, int segbase0, int segbase1, int c0,
    int nrows) {
  const int half = threadIdx.x >> 5;  // 0..7
  const int lane = threadIdx.x & 31;
  const int d = blockIdx.x * 8 + half;
  const int slot = blockIdx.y;
  if (d >= nrows) return;
  const int s = (slot == 0 ? segbase0 : segbase1) + c0 + d;
  const int lo = off[s], hi = off[s + 1];
  const float iv = invdeg[s];
  float a0 = 0.f, a1 = 0.f, a2 = 0.f, a3 = 0.f;
  float a4 = 0.f, a5 = 0.f, a6 = 0.f, a7 = 0.f;
  const unsigned short* xl = x + lane * 8;
  int e = lo;
  for (; e + 3 < hi; e += 4) {
    const int s0 = elist[e], s1 = elist[e + 1];
    const int s2 = elist[e + 2], s3 = elist[e + 3];
    const uint4 v0 = *(const uint4*)(xl + (size_t)s0 * kH);
    const uint4 v1 = *(const uint4*)(xl + (size_t)s1 * kH);
    const uint4 v2 = *(const uint4*)(xl + (size_t)s2 * kH);
    const uint4 v3 = *(const uint4*)(xl + (size_t)s3 * kH);
    a0 += b2f((unsigned short)v0.x) + b2f((unsigned short)v1.x) +
          b2f((unsigned short)v2.x) + b2f((unsigned short)v3.x);
    a1 += b2f((unsigned short)(v0.x >> 16)) + b2f((unsigned short)(v1.x >> 16)) +
          b2f((unsigned short)(v2.x >> 16)) + b2f((unsigned short)(v3.x >> 16));
    a2 += b2f((unsigned short)v0.y) + b2f((unsigned short)v1.y) +
          b2f((unsigned short)v2.y) + b2f((unsigned short)v3.y);
    a3 += b2f((unsigned short)(v0.y >> 16)) + b2f((unsigned short)(v1.y >> 16)) +
          b2f((unsigned short)(v2.y >> 16)) + b2f((unsigned short)(v3.y >> 16));
    a4 += b2f((unsigned short)v0.z) + b2f((unsigned short)v1.z) +
          b2f((unsigned short)v2.z) + b2f((unsigned short)v3.z);
    a5 += b2f((unsigned short)(v0.z >> 16)) + b2f((unsigned short)(v1.z >> 16)) +
          b2f((unsigned short)(v2.z >> 16)) + b2f((unsigned short)(v3.z >> 16));
    a6 += b2f((unsigned short)v0.w) + b2f((unsigned short)v1.w) +
          b2f((unsigned short)v2.w) + b2f((unsigned short)v3.w);
    a7 += b2f((unsigned short)(v0.w >> 16)) + b2f((unsigned short)(v1.w >> 16)) +
          b2f((unsigned short)(v2.w >> 16)) + b2f((unsigned short)(v3.w >> 16));
  }
  for (; e < hi; ++e) {
    const int s0 = elist[e];
    const uint4 v0 = *(const uint4*)(xl + (size_t)s0 * kH);
    a0 += b2f((unsigned short)v0.x);
    a1 += b2f((unsigned short)(v0.x >> 16));
    a2 += b2f((unsigned short)v0.y);
    a3 += b2f((unsigned short)(v0.y >> 16));
    a4 += b2f((unsigned short)v0.z);
    a5 += b2f((unsigned short)(v0.z >> 16));
    a6 += b2f((unsigned short)v0.w);
    a7 += b2f((unsigned short)(v0.w >> 16));
  }
  uint4 o;
  o.x = (unsigned int)f2b(a0 * iv) | ((unsigned int)f2b(a1 * iv) << 16);
  o.y = (unsigned int)f2b(a2 * iv) | ((unsigned int)f2b(a3 * iv) << 16);
  o.z = (unsigned int)f2b(a4 * iv) | ((unsigned int)f2b(a5 * iv) << 16);
  o.w = (unsigned int)f2b(a6 * iv) | ((unsigned int)f2b(a7 * iv) << 16);
  *(uint4*)&Aagg[(size_t)d * kKA + slot * kH + lane * 8] = o;
}

// ---------------------------------------------------------------------------
// Fused MFMA GEMM + LayerNorm + leaky + residual.  512 threads, 8 waves.
//   acc = [Aagg | xcur] @ Bt^T + bias   (K=768, BK=32, 24 K-tiles)
// Tile 64 rows x 256 cols; wave w owns cols w*32 (4 m-frags x 2 n-frags
// = 8 MFMA/iter). A[3][64][32] + B[3][256][32] LDS, staged via
// global_load_lds: waves 0-3 stage A rows w*16.. + B rows w*32..; waves
// 4-7 stage B rows w*32.. only. Counted vmcnt (own loads) never drains
// to 0 in the main loop; one s_barrier per K-tile.
// ---------------------------------------------------------------------------
__global__ __launch_bounds__(512) void k_gemm_fused(
    const unsigned short* __restrict__ Aagg,
    const unsigned short* __restrict__ xcur, unsigned short* __restrict__ xnxt,
    const unsigned short* __restrict__ Bt, const float* __restrict__ bias,
    const float* __restrict__ gamma, const float* __restrict__ beta, int M,
    int grow0) {
  __shared__ __align__(16) unsigned short As[3][64][32];
  __shared__ __align__(16) unsigned short Bs[3][256][32];
  __shared__ float redS[8][64];
  __shared__ float redQ[8][64];
  __shared__ float stat[64][2];

  const int tid = threadIdx.x;
  const int wave = tid >> 6;    // 0..7
  const int lane = tid & 63;
  const int fr = lane & 15;
  const int fq = lane >> 4;
  const int ncol0 = wave * 32;  // wave's 32 output cols
  const int brow = blockIdx.x * 64;

  // staging lane decomposition: 4 lanes per row (16B granules), 16 rows/instr
  const int srow = lane >> 2;                      // 0..15
  const int sg = (lane & 3) ^ swz16(srow);         // swizzled source granule
  // A: waves 0-3 stage rows w*16 .. w*16+15
  const unsigned short* Asrc_agg =
      Aagg + (size_t)(brow + wave * 16 + srow) * kKA + sg * 8;
  const unsigned short* Asrc_x =
      xcur + (size_t)(grow0 + brow + wave * 16 + srow) * kH + sg * 8;
  // B: wave w stages rows w*32 + srow and w*32 + 16 + srow
  const unsigned short* Bsrc = Bt + (size_t)(wave * 32 + srow) * kK + sg * 8;

#define STAGE(buf, t)                                                         \
  do {                                                                        \
    const int kb_ = (t) * 32;                                                 \
    if (wave < 4)                                                             \
      gload16((kb_ < kKA) ? (Asrc_agg + kb_) : (Asrc_x + (kb_ - kKA)),        \
              &As[buf][wave * 16][0]);                                        \
    gload16(Bsrc + kb_, &Bs[buf][wave * 32][0]);                              \
    gload16(Bsrc + (size_t)16 * kK + kb_, &Bs[buf][wave * 32 + 16][0]);       \
  } while (0)
#define WAIT_OWN()                                                            \
  do {                                                                        \
    if (wave < 4)                                                             \
      asm volatile("s_waitcnt vmcnt(3)" ::: "memory");                        \
    else                                                                      \
      asm volatile("s_waitcnt vmcnt(2)" ::: "memory");                        \
  } while (0)

  float4v acc[4][2];
#pragma unroll
  for (int mi = 0; mi < 4; ++mi)
#pragma unroll
    for (int ni = 0; ni < 2; ++ni) acc[mi][ni] = (float4v)(0.f);

  const int rg = swz16(fr);  // read-side swizzle component

  // prologue: stage tiles 0 and 1; wait tile 0 (leave tile 1 in flight)
  STAGE(0, 0);
  STAGE(1, 1);
  WAIT_OWN();
  asm volatile("s_barrier" ::: "memory");

  for (int t = 0; t < 24; ++t) {
    const int cur = t % 3;
    // 1. read this tile's fragments into registers
    short8v afrag[4], bfrag[2];
#pragma unroll
    for (int mi = 0; mi < 4; ++mi)
      afrag[mi] = *(const short8v*)&As[cur][mi * 16 + fr][((fq ^ rg) & 3) * 8];
#pragma unroll
    for (int ni = 0; ni < 2; ++ni)
      bfrag[ni] =
          *(const short8v*)&Bs[cur][ncol0 + ni * 16 + fr][((fq ^ rg) & 3) * 8];
    asm volatile("s_waitcnt lgkmcnt(0)" ::: "memory");
    // 2. issue stage for tile t+2 (overwrites buf (t-1)%3 -- reads done)
    if (t < 22) STAGE((t + 2) % 3, t + 2);
    // 3. compute (reg-only; loads for t+1/t+2 fly underneath)
#pragma unroll
    for (int mi = 0; mi < 4; ++mi)
#pragma unroll
      for (int ni = 0; ni < 2; ++ni)
        acc[mi][ni] = __builtin_amdgcn_mfma_f32_16x16x32_bf16(
            afrag[mi], bfrag[ni], acc[mi][ni], 0, 0, 0);
    // 4. counted wait: own tile-(t+1) loads landed, t+2 still in flight
    if (t < 22) {
      WAIT_OWN();
    } else {
      asm volatile("s_waitcnt vmcnt(0)" ::: "memory");
    }
    asm volatile("s_barrier" ::: "memory");
  }
#undef STAGE
#undef WAIT_OWN

  // ---- fused epilogue: bias, LN stats, leaky, residual, bf16 store ----
  float bb[2], gam[2], bet[2];
#pragma unroll
  for (int ni = 0; ni < 2; ++ni) {
    const int col = ncol0 + ni * 16 + fr;
    bb[ni] = bias[col];
    gam[ni] = gamma[col];
    bet[ni] = beta[col];
  }
#pragma unroll
  for (int mi = 0; mi < 4; ++mi)
#pragma unroll
    for (int ni = 0; ni < 2; ++ni)
#pragma unroll
      for (int reg = 0; reg < 4; ++reg) acc[mi][ni][reg] += bb[ni];

#pragma unroll
  for (int mi = 0; mi < 4; ++mi) {
#pragma unroll
    for (int reg = 0; reg < 4; ++reg) {
      float s = 0.f, q = 0.f;
#pragma unroll
      for (int ni = 0; ni < 2; ++ni) {
        const float v = acc[mi][ni][reg];
        s += v;
        q += v * v;
      }
#pragma unroll
      for (int o = 1; o < 16; o <<= 1) {
        s += __shfl_xor(s, o);
        q += __shfl_xor(q, o);
      }
      if (fr == 0) {
        const int rl = mi * 16 + fq * 4 + reg;
        redS[wave][rl] = s;
        redQ[wave][rl] = q;
      }
    }
  }
  __syncthreads();
  if (tid < 64) {
    float s = 0.f, q = 0.f;
#pragma unroll
    for (int w = 0; w < 8; ++w) {
      s += redS[w][tid];
      q += redQ[w][tid];
    }
    const float mu = s * (1.f / kH);
    const float var = q * (1.f / kH) - mu * mu;
    stat[tid][0] = mu;
    stat[tid][1] = rsqrtf(var + 1e-5f);
  }
  __syncthreads();

#pragma unroll
  for (int mi = 0; mi < 4; ++mi) {
#pragma unroll
    for (int reg = 0; reg < 4; ++reg) {
      const int rl = mi * 16 + fq * 4 + reg;
      const int r = brow + rl;
      if (r >= M) continue;
      const float mu = stat[rl][0];
      const float rs = stat[rl][1];
      const size_t gr = (size_t)(grow0 + r) * kH;
#pragma unroll
      for (int ni = 0; ni < 2; ++ni) {
        const int col = ncol0 + ni * 16 + fr;
        float t = (acc[mi][ni][reg] - mu) * rs * gam[ni] + bet[ni];
        t = t > 0.f ? t : 0.1f * t;
        const float xo = b2f(xcur[gr + col]);
        xnxt[gr + col] = f2b(xo + t);
      }
    }
  }
}

// ---------------------------------------------------------------------------
// Readout: out[n] = dot(x[n], ro_w) + ro_b  (flight rows), fp32 out.
// ---------------------------------------------------------------------------
__global__ __launch_bounds__(256) void k_readout(
    const unsigned short* __restrict__ x, const float* __restrict__ w,
    const float* __restrict__ b, float* __restrict__ out) {
  const int wave = threadIdx.x >> 6;
  const int lane = threadIdx.x & 63;
  const int row = blockIdx.x * 4 + wave;
  if (row >= kNF) return;
  const ushort4 v = *(const ushort4*)&x[(size_t)row * kH + (lane << 2)];
  const float4 wv = *(const float4*)&w[lane << 2];
  float s = b2f(v.x) * wv.x + b2f(v.y) * wv.y + b2f(v.z) * wv.z +
            b2f(v.w) * wv.w;
#pragma unroll
  for (int o = 1; o < 64; o <<= 1) s += __shfl_xor(s, o);
  if (lane == 0) out[row] = s + b[0];
}

}  // namespace

// ---------------------------------------------------------------------------
extern "C" void kernel_launch(void* const* d_in, const int* in_sizes, int n_in,
                              void* d_out, int out_size, void* d_ws,
                              size_t ws_size, hipStream_t stream) {
  const float* x_flight = (const float*)d_in[0];
  const float* x_airport = (const float*)d_in[1];
  const float* enc_w_f = (const float*)d_in[2];
  const float* enc_b_f = (const float*)d_in[3];
  const float* enc_w_a = (const float*)d_in[4];
  const float* enc_b_a = (const float*)d_in[5];
  const float* basis = (const float*)d_in[6];
  const float* comp = (const float*)d_in[7];
  const float* root = (const float*)d_in[8];
  const float* conv_bias = (const float*)d_in[9];
  const float* ln_gamma = (const float*)d_in[10];
  const float* ln_beta = (const float*)d_in[11];
  const float* ro_w = (const float*)d_in[12];
  const float* ro_b = (const float*)d_in[13];
  const int* ei_fa = (const int*)d_in[14];
  const int* ei_af = (const int*)d_in[15];
  const int* ei_ff = (const int*)d_in[16];
  const int* ei_aa = (const int*)d_in[17];
  float* out = (float*)d_out;

  // workspace carve (fixed buffers first, then adaptive A-chunk)
  char* base = (char*)d_ws;
  size_t off_b = 0;
  auto carve = [&](size_t bytes) -> char* {
    char* p = base + off_b;
    off_b += (bytes + 255) & ~(size_t)255;
    return p;
  };
  unsigned short* xbuf = (unsigned short*)carve((size_t)kN * kH * 2);
  unsigned short* hbuf = (unsigned short*)carve((size_t)kN * kH * 2);
  unsigned short* BtF = (unsigned short*)carve((size_t)kK * kH * 2);
  unsigned short* BtA = (unsigned short*)carve((size_t)kK * kH * 2);
  unsigned short* WtF = (unsigned short*)carve((size_t)kH * 32 * 2);
  unsigned short* WtA = (unsigned short*)carve((size_t)kH * 32 * 2);
  int* cnt = (int*)carve((size_t)kSEG * 4);
  int* offs = (int*)carve((size_t)(kSEG + 1) * 4);
  int* cursor = (int*)carve((size_t)kSEG * 4);
  int* elist = (int*)carve((size_t)kETOT * 4);
  int* bsum = (int*)carve((size_t)kScanBlocks * 4);
  int* bpre = (int*)carve((size_t)kScanBlocks * 4);
  float* invdeg = (float*)carve((size_t)kSEG * 4);
  // adaptive chunk rows (multiple of 64, cap 102400 = full flight set) + 64
  // pad rows for the fragment over-read (GEMM stages rows up to M+63)
  size_t rem = (ws_size > off_b + 4096) ? (ws_size - off_b - 4096) : 0;
  int CH = (int)(rem / ((size_t)kKA * 2)) - 64;
  if (CH > 102400) CH = 102400;
  CH &= ~63;
  if (CH < 64) CH = 64;  // (ws_size too small to function; best effort)
  unsigned short* Achunk = (unsigned short*)carve((size_t)(CH + 64) * kKA * 2);

  // --- encoders (MFMA) ---
  k_build_encWt<<<(2 * kH * 32 + 255) / 256, 256, 0, stream>>>(enc_w_f, enc_w_a,
                                                               WtF, WtA);
  k_enc_mfma<32><<<(kNF + 63) / 64, 256, 0, stream>>>(x_flight, WtF, enc_b_f,
                                                      xbuf, kNF, 0);
  k_enc_mfma<16><<<(kNA + 63) / 64, 256, 0, stream>>>(x_airport, WtA, enc_b_a,
                                                      xbuf, kNA, kNF);

  // --- CSR build ---
  hipMemsetAsync(cnt, 0, (size_t)kSEG * 4, stream);
  const int b0 = 0, b1 = kNA, b2 = kNA + kNF, b3 = kNA + 2 * kNF;
  k_count_all<<<(kETOT + 255) / 256, 256, 0, stream>>>(ei_fa, ei_af, ei_ff,
                                                       ei_aa, cnt);
  k_scan1<<<kScanBlocks, 256, 0, stream>>>(cnt, offs, bsum, invdeg);
  k_scan2<<<1, 256, 0, stream>>>(bsum, bpre);
  k_scan3<<<(kSEG + 255) / 256, 256, 0, stream>>>(offs, cursor, bpre);
  k_fill_all<<<(kETOT + 255) / 256, 256, 0, stream>>>(ei_fa, ei_af, ei_ff,
                                                      ei_aa, cursor, elist);

  // --- layers (ping-pong x buffers) ---
  unsigned short* bufs[2] = {xbuf, hbuf};
  int curb = 0;
  for (int l = 0; l < kL; ++l) {
    const float* comp_l = comp + (size_t)l * 4 * kB;
    const float* basis_l = basis + (size_t)l * kB * kH * kH;
    const float* root_l = root + (size_t)l * kH * kH;
    const float* bias_l = conv_bias + (size_t)l * kH;
    const float* gamma_l = ln_gamma + (size_t)l * kH;
    const float* beta_l = ln_beta + (size_t)l * kH;
    const unsigned short* xc = bufs[curb];
    unsigned short* xn = bufs[curb ^ 1];

    k_build_Bt<<<(2 * kK * kH + 255) / 256, 256, 0, stream>>>(comp_l, basis_l,
                                                              root_l, BtF, BtA);

    // flight rows: slots {r1(af), r2(ff)}, x rows [0, kNF)
    for (int c0 = 0; c0 < kNF; c0 += CH) {
      const int rows = (kNF - c0 < CH) ? (kNF - c0) : CH;
      dim3 gg((rows + 7) / 8, 2);
      k_gather2<<<gg, 256, 0, stream>>>(xc, Achunk, offs, elist, invdeg, b1,
                                        b2, c0, rows);
      dim3 g((rows + 63) / 64);
      k_gemm_fused<<<g, 512, 0, stream>>>(Achunk, xc, xn, BtF, bias_l, gamma_l,
                                          beta_l, rows, c0);
    }
    // airport rows: slots {r0(fa), r3(aa)}, x rows [kNF, kN)
    for (int c0 = 0; c0 < kNA; c0 += CH) {
      const int rows = (kNA - c0 < CH) ? (kNA - c0) : CH;
      dim3 gg((rows + 7) / 8, 2);
      k_gather2<<<gg, 256, 0, stream>>>(xc, Achunk, offs, elist, invdeg, b0,
                                        b3, c0, rows);
      dim3 g((rows + 63) / 64);
      k_gemm_fused<<<g, 512, 0, stream>>>(Achunk, xc, xn, BtA, bias_l, gamma_l,
                                          beta_l, rows, kNF + c0);
    }
    curb ^= 1;
  }

  // --- readout ---
  k_readout<<<(kNF + 3) / 4, 256, 0, stream>>>(bufs[curb], ro_w, ro_b, out);
}